// Round 14
// baseline (96.741 us; speedup 1.0000x reference)
//
#include <hip/hip_runtime.h>
#include <math.h>

#define ROWS_TOTAL 8192
#define KDIM 4096
#define NJ 25
#define NTHREADS 512
#define KSPLIT 16
#define KQ 256          // k per block
#define NS 8            // K-steps of 32
#define ACC_FLOATS (64 * NJ * 128)   // 204800 floats = 819.2 KB

typedef __attribute__((ext_vector_type(8))) short bf16x8;
typedef __attribute__((ext_vector_type(4))) float f32x4;

// gfx950 packed f32->bf16 (RNE); dst.lo=bf16(lo), dst.hi=bf16(hi)
__device__ __forceinline__ unsigned cvt_pk_bf16(float lo, float hi) {
    unsigned r;
    asm("v_cvt_pk_bf16_f32 %0, %1, %2" : "=v"(r) : "v"(lo), "v"(hi));
    return r;
}

union BF { uint4 u4; bf16x8 h; };

__device__ __forceinline__ float sigmoidf_(float z) {
    return 1.f / (1.f + __expf(-z));
}

// ------------------------------------------------------------------
// Fused kernel: R5-structure main (B LDS-staged, 32 waves/CU, direct
// fragment x-loads) + FENCE-FREE ticket epilogue via device atomics.
// grid = 1024 blocks (64 row-groups x 16 k-slices) x 512 threads.
// Partials accumulate with atomicAdd into acc[g][j(25)][row(128)]
// (zeroed by hipMemsetAsync each call -> replay-safe, deterministic
// work). __syncthreads() drains vmcnt => adds complete at the
// coherence point before the ticket; NO __threadfence (R7/R8: agent
// fences emit L2 writeback/invalidate -> 10x slowdown).
// The 16th arrival per group reads sums via atomicAdd(p, 0.0f)
// (coherent read; plain loads risk stale zeros in the memset-writer's
// XCD L2) and runs the per-cell Sinkhorn epilogue in-block.
// ------------------------------------------------------------------
__global__ __launch_bounds__(NTHREADS) void mhc_fused(
    const float* __restrict__ x,
    const float* __restrict__ rmsw,
    const float* __restrict__ phi_pre,
    const float* __restrict__ phi_post,
    const float* __restrict__ phi_res,
    float* __restrict__ acc,
    unsigned* __restrict__ cnt,
    const float* __restrict__ b_pre,
    const float* __restrict__ b_post,
    const float* __restrict__ b_res,
    const float* __restrict__ a_pre,
    const float* __restrict__ a_post,
    const float* __restrict__ a_res,
    float* __restrict__ out)
{
    __shared__ uint4 bfrag[NS * 2 * 64];   // 16 KB; reused as sm[] in epilogue
    __shared__ unsigned last_flag;

    const int t    = threadIdx.x;
    const int wave = t >> 6;
    const int lane = t & 63;
    const int bid  = blockIdx.x;
    const int g    = bid >> 4;     // row group 0..63 (128 rows each)
    const int q    = bid & 15;     // k slice
    const int kq0  = q * KQ;

    // ---- stage B fragments (one-time); FPT = 2 ----
    #pragma unroll
    for (int f = 0; f < 2; ++f) {
        const int fid = f * NTHREADS + t;
        const int s   = fid >> 7;
        const int n   = (fid >> 6) & 1;
        const int ln  = fid & 63;
        const int col = n * 16 + (ln & 15);
        const int kl  = s * 32 + 8 * (ln >> 4);
        float v[8];
        #pragma unroll
        for (int j = 0; j < 8; ++j) {
            const int k = kq0 + kl + j;
            float vv = 0.f;
            if (col < 4)       vv = rmsw[k] * phi_pre[k * 4 + col];
            else if (col < 8)  vv = rmsw[k] * phi_post[k * 4 + (col - 4)];
            else if (col < 24) vv = rmsw[k] * phi_res[k * 16 + (col - 8)];
            v[j] = vv;
        }
        uint4 pk;
        pk.x = cvt_pk_bf16(v[0], v[1]);
        pk.y = cvt_pk_bf16(v[2], v[3]);
        pk.z = cvt_pk_bf16(v[4], v[5]);
        pk.w = cvt_pk_bf16(v[6], v[7]);
        bfrag[(s * 2 + n) * 64 + ln] = pk;
    }
    __syncthreads();

    // ---- main loop (R5-proven: direct x frag loads, no barriers) ----
    const int row = g * 128 + wave * 16 + (lane & 15);
    const float* xr = x + (size_t)row * KDIM + kq0 + 8 * (lane >> 4);

    f32x4 acc0 = {0.f, 0.f, 0.f, 0.f};
    f32x4 acc1 = {0.f, 0.f, 0.f, 0.f};
    float ssq0 = 0.f, ssq1 = 0.f;

    #pragma unroll 4
    for (int s = 0; s < NS; ++s) {
        const float4 a0 = *(const float4*)(xr + 32 * s);
        const float4 a1 = *(const float4*)(xr + 32 * s + 4);
        ssq0 = fmaf(a0.x, a0.x, ssq0);
        ssq0 = fmaf(a0.y, a0.y, ssq0);
        ssq0 = fmaf(a0.z, a0.z, ssq0);
        ssq0 = fmaf(a0.w, a0.w, ssq0);
        ssq1 = fmaf(a1.x, a1.x, ssq1);
        ssq1 = fmaf(a1.y, a1.y, ssq1);
        ssq1 = fmaf(a1.z, a1.z, ssq1);
        ssq1 = fmaf(a1.w, a1.w, ssq1);
        BF af;
        af.u4.x = cvt_pk_bf16(a0.x, a0.y);
        af.u4.y = cvt_pk_bf16(a0.z, a0.w);
        af.u4.z = cvt_pk_bf16(a1.x, a1.y);
        af.u4.w = cvt_pk_bf16(a1.z, a1.w);
        BF b0, b1;
        b0.u4 = bfrag[(s * 2 + 0) * 64 + lane];
        b1.u4 = bfrag[(s * 2 + 1) * 64 + lane];
        acc0 = __builtin_amdgcn_mfma_f32_16x16x32_bf16(af.h, b0.h, acc0, 0, 0, 0);
        acc1 = __builtin_amdgcn_mfma_f32_16x16x32_bf16(af.h, b1.h, acc1, 0, 0, 0);
    }

    float ssq = ssq0 + ssq1;
    ssq += __shfl_xor(ssq, 16);
    ssq += __shfl_xor(ssq, 32);

    // ---- accumulate partials: device-scope atomics (no fences) ----
    float* accg = acc + g * (NJ * 128);
    const int lr = wave * 16 + 4 * (lane >> 4);   // local row base
    const int c0 = lane & 15;
    #pragma unroll
    for (int r = 0; r < 4; ++r)
        atomicAdd(&accg[c0 * 128 + lr + r], acc0[r]);
    if (c0 < 8) {
        #pragma unroll
        for (int r = 0; r < 4; ++r)
            atomicAdd(&accg[(16 + c0) * 128 + lr + r], acc1[r]);
    }
    if (lane < 16)
        atomicAdd(&accg[24 * 128 + wave * 16 + lane], ssq);

    // ---- ticket (vmcnt drained by the barrier => adds complete) ----
    __syncthreads();
    if (t == 0) {
        const unsigned old = atomicAdd(&cnt[g], 1u);
        last_flag = (old == (unsigned)(KSPLIT - 1));
    }
    __syncthreads();
    if (!last_flag) return;

    // ---- epilogue (last block of group g): coherent atomic reads ----
    float* sm = (float*)bfrag;     // 25*132 = 3300 floats <= 4096
    for (int i = t; i < NJ * 128; i += NTHREADS) {
        const int j = i >> 7;
        const int rr = i & 127;
        sm[j * 132 + rr] = atomicAdd(&accg[i], 0.0f);
    }
    __syncthreads();

    // 128 rows x 16 cells, 4 passes of 32 rows on 512 threads
    #pragma unroll
    for (int pass = 0; pass < 4; ++pass) {
        const int rr   = pass * 32 + (t >> 4);   // local row 0..127
        const int cell = t & 15;                 // i*4 + jc
        const int gr   = g * 128 + rr;

        const float scale = rsqrtf(sm[24 * 132 + rr] * (1.0f / KDIM) + 1e-6f);

        if (cell < 4) {
            out[gr * 4 + cell] =
                sigmoidf_(fmaf(a_pre[0] * scale, sm[cell * 132 + rr], b_pre[cell]));
        } else if (cell < 8) {
            out[32768 + gr * 4 + (cell - 4)] =
                2.f * sigmoidf_(fmaf(a_post[0] * scale, sm[cell * 132 + rr], b_post[cell - 4]));
        }

        float m = __expf(fmaf(a_res[0] * scale, sm[(8 + cell) * 132 + rr], b_res[cell]));
        for (int it = 0; it < 20; ++it) {
            float s = m + __shfl_xor(m, 1);      // row sum over jc (cell bits 0,1)
            s += __shfl_xor(s, 2);
            m /= s;
            float c = m + __shfl_xor(m, 4);      // col sum over i (cell bits 2,3)
            c += __shfl_xor(c, 8);
            m /= c;
        }
        out[65536 + gr * 16 + cell] = m;
    }
}

// ------------------------------------------------------------------
// Fallback (tiny ws, needs only 256 KB): R12/R13 pack + full pair.
// ------------------------------------------------------------------
__global__ __launch_bounds__(512) void mhc_pack(
    const float* __restrict__ rmsw,
    const float* __restrict__ phi_pre,
    const float* __restrict__ phi_post,
    const float* __restrict__ phi_res,
    uint4* __restrict__ packed)
{
    const int fid = blockIdx.x * 512 + threadIdx.x;
    const int s   = fid >> 7;
    const int n   = (fid >> 6) & 1;
    const int ln  = fid & 63;
    const int col = n * 16 + (ln & 15);
    const int kl  = s * 32 + 8 * (ln >> 4);
    float v[8];
    #pragma unroll
    for (int j = 0; j < 8; ++j) {
        const int k = kl + j;
        float vv = 0.f;
        if (col < 4)       vv = rmsw[k] * phi_pre[k * 4 + col];
        else if (col < 8)  vv = rmsw[k] * phi_post[k * 4 + (col - 4)];
        else if (col < 24) vv = rmsw[k] * phi_res[k * 16 + (col - 8)];
        v[j] = vv;
    }
    uint4 pk;
    pk.x = cvt_pk_bf16(v[0], v[1]);
    pk.y = cvt_pk_bf16(v[2], v[3]);
    pk.z = cvt_pk_bf16(v[4], v[5]);
    pk.w = cvt_pk_bf16(v[6], v[7]);
    packed[fid] = pk;
}

__global__ __launch_bounds__(1024) void mhc_full(
    const float* __restrict__ x,
    const uint4* __restrict__ packed,
    const float* __restrict__ b_pre,
    const float* __restrict__ b_post,
    const float* __restrict__ b_res,
    const float* __restrict__ a_pre,
    const float* __restrict__ a_post,
    const float* __restrict__ a_res,
    float* __restrict__ out)
{
    __shared__ float red[16 * 9 * 64];

    const int t    = threadIdx.x;
    const int wave = t >> 6;
    const int lane = t & 63;
    const int g    = blockIdx.x;

    const int row = g * 16 + (lane & 15);
    const float* xr = x + (size_t)row * KDIM + wave * 256 + 8 * (lane >> 4);
    const uint4* pb = packed + wave * (8 * 2 * 64);

    f32x4 acc0 = {0.f, 0.f, 0.f, 0.f};
    f32x4 acc1 = {0.f, 0.f, 0.f, 0.f};
    float ssq0 = 0.f, ssq1 = 0.f;

    #pragma unroll 4
    for (int s = 0; s < 8; ++s) {
        const float4 a0 = *(const float4*)(xr + 32 * s);
        const float4 a1 = *(const float4*)(xr + 32 * s + 4);
        ssq0 = fmaf(a0.x, a0.x, ssq0); ssq0 = fmaf(a0.y, a0.y, ssq0);
        ssq0 = fmaf(a0.z, a0.z, ssq0); ssq0 = fmaf(a0.w, a0.w, ssq0);
        ssq1 = fmaf(a1.x, a1.x, ssq1); ssq1 = fmaf(a1.y, a1.y, ssq1);
        ssq1 = fmaf(a1.z, a1.z, ssq1); ssq1 = fmaf(a1.w, a1.w, ssq1);
        BF af;
        af.u4.x = cvt_pk_bf16(a0.x, a0.y);
        af.u4.y = cvt_pk_bf16(a0.z, a0.w);
        af.u4.z = cvt_pk_bf16(a1.x, a1.y);
        af.u4.w = cvt_pk_bf16(a1.z, a1.w);
        BF b0, b1;
        b0.u4 = pb[(s * 2 + 0) * 64 + lane];
        b1.u4 = pb[(s * 2 + 1) * 64 + lane];
        acc0 = __builtin_amdgcn_mfma_f32_16x16x32_bf16(af.h, b0.h, acc0, 0, 0, 0);
        acc1 = __builtin_amdgcn_mfma_f32_16x16x32_bf16(af.h, b1.h, acc1, 0, 0, 0);
    }

    float ssq = ssq0 + ssq1;
    ssq += __shfl_xor(ssq, 16);
    ssq += __shfl_xor(ssq, 32);

    float* myred = red + wave * 576;
    #pragma unroll
    for (int r = 0; r < 4; ++r) myred[r * 64 + lane] = acc0[r];
    #pragma unroll
    for (int r = 0; r < 4; ++r) myred[(4 + r) * 64 + lane] = acc1[r];
    myred[8 * 64 + lane] = ssq;
    __syncthreads();

    if (t < 576) {
        float s = red[t];
        #pragma unroll
        for (int q = 1; q < 16; ++q)
            s += red[q * 576 + t];
        red[t] = s;
    }
    __syncthreads();

    if (t < 256) {
        const int rr   = t >> 4;
        const int cell = t & 15;
        const int gr   = g * 16 + rr;

        const float scale = rsqrtf(red[8 * 64 + rr] * (1.0f / KDIM) + 1e-6f);
        const int li = 16 * (rr >> 2);
        const int j0 = rr & 3;

        if (cell < 4) {
            const float v = red[j0 * 64 + li + cell];
            out[gr * 4 + cell] = sigmoidf_(fmaf(a_pre[0] * scale, v, b_pre[cell]));
        } else if (cell < 8) {
            const float v = red[j0 * 64 + li + cell];
            out[32768 + gr * 4 + (cell - 4)] =
                2.f * sigmoidf_(fmaf(a_post[0] * scale, v, b_post[cell - 4]));
        }

        const int col   = 8 + cell;
        const int jslot = j0 + (col < 16 ? 0 : 4);
        const float v   = red[jslot * 64 + (col & 15) + li];
        float m = __expf(fmaf(a_res[0] * scale, v, b_res[cell]));
        for (int it = 0; it < 20; ++it) {
            float s = m + __shfl_xor(m, 1);
            s += __shfl_xor(s, 2);
            m /= s;
            float c = m + __shfl_xor(m, 4);
            c += __shfl_xor(c, 8);
            m /= c;
        }
        out[65536 + gr * 16 + cell] = m;
    }
}

extern "C" void kernel_launch(void* const* d_in, const int* in_sizes, int n_in,
                              void* d_out, int out_size, void* d_ws, size_t ws_size,
                              hipStream_t stream) {
    const float* x      = (const float*)d_in[0];
    const float* rmsw   = (const float*)d_in[1];
    const float* ppre   = (const float*)d_in[2];
    const float* ppost  = (const float*)d_in[3];
    const float* pres   = (const float*)d_in[4];
    const float* b_pre  = (const float*)d_in[5];
    const float* b_post = (const float*)d_in[6];
    const float* b_res  = (const float*)d_in[7];
    const float* a_pre  = (const float*)d_in[8];
    const float* a_post = (const float*)d_in[9];
    const float* a_res  = (const float*)d_in[10];
    float* out = (float*)d_out;

    const size_t need = (size_t)ACC_FLOATS * 4 + 256;   // 819.2 KB + cnt
    if (ws_size >= need) {
        float* acc = (float*)d_ws;
        unsigned* cnt = (unsigned*)((char*)d_ws + (size_t)ACC_FLOATS * 4);
        hipMemsetAsync(d_ws, 0, need, stream);
        hipLaunchKernelGGL(mhc_fused, dim3(1024), dim3(NTHREADS), 0, stream,
                           x, rmsw, ppre, ppost, pres, acc, cnt,
                           b_pre, b_post, b_res, a_pre, a_post, a_res, out);
    } else {
        uint4* packed = (uint4*)d_ws;   // 256 KB
        hipLaunchKernelGGL(mhc_pack, dim3(32), dim3(512), 0, stream,
                           rmsw, ppre, ppost, pres, packed);
        hipLaunchKernelGGL(mhc_full, dim3(512), dim3(1024), 0, stream,
                           x, packed, b_pre, b_post, b_res,
                           a_pre, a_post, a_res, out);
    }
}

// Round 15
// 45.330 us; speedup vs baseline: 2.1341x; 2.1341x over previous
//
#include <hip/hip_runtime.h>
#include <math.h>

#define ROWS_TOTAL 8192
#define KDIM 4096
#define NJ 25
#define BM 32            // rows per main block (two 16-row tiles)
#define NWAVE 16         // waves per main block (1024 threads)
#define NSW 8            // K-steps per wave (KDIM/32/NWAVE)

typedef __attribute__((ext_vector_type(8))) short bf16x8;
typedef __attribute__((ext_vector_type(4))) float f32x4;

// pure-C f32->bf16 RNE (R5-proven). NO inline asm: m240 (guide T12)
// says hand-written cvt_pk asm is -37% -- it blocks the scheduler from
// reordering loads across the convert chain. The compiler can fuse
// this pattern itself when profitable.
__device__ __forceinline__ unsigned short f2bf(float f) {
    union { float f; unsigned u; } v; v.f = f;
    return (unsigned short)((v.u + 0x7FFFu + ((v.u >> 16) & 1u)) >> 16);
}
__device__ __forceinline__ unsigned pkbf(float lo, float hi) {
    return (unsigned)f2bf(lo) | ((unsigned)f2bf(hi) << 16);
}

union BF { uint4 u4; bf16x8 h; };

__device__ __forceinline__ float sigmoidf_(float z) {
    return 1.f / (1.f + __expf(-z));
}

// ------------------------------------------------------------------
// Kernel 0: pack B = (rmsw * phi) into MFMA-fragment order, bf16.
// ------------------------------------------------------------------
__global__ __launch_bounds__(512) void mhc_pack(
    const float* __restrict__ rmsw,
    const float* __restrict__ phi_pre,
    const float* __restrict__ phi_post,
    const float* __restrict__ phi_res,
    uint4* __restrict__ packed)
{
    const int fid = blockIdx.x * 512 + threadIdx.x;   // 0..16383
    const int s   = fid >> 7;
    const int n   = (fid >> 6) & 1;
    const int ln  = fid & 63;
    const int col = n * 16 + (ln & 15);
    const int kl  = s * 32 + 8 * (ln >> 4);
    float v[8];
    #pragma unroll
    for (int j = 0; j < 8; ++j) {
        const int k = kl + j;
        float vv = 0.f;
        if (col < 4)       vv = rmsw[k] * phi_pre[k * 4 + col];
        else if (col < 8)  vv = rmsw[k] * phi_post[k * 4 + (col - 4)];
        else if (col < 24) vv = rmsw[k] * phi_res[k * 16 + (col - 8)];
        v[j] = vv;
    }
    uint4 pk;
    pk.x = pkbf(v[0], v[1]);
    pk.y = pkbf(v[2], v[3]);
    pk.z = pkbf(v[4], v[5]);
    pk.w = pkbf(v[6], v[7]);
    packed[fid] = pk;
}

// ------------------------------------------------------------------
// Kernel 1: full-K fused projection + epilogue, BM=32 (two row tiles).
// 256 blocks x 1024 threads. Wave w covers k in [256w, 256w+256);
// per K-step: 4 x-loads + 2 B-loads + 4 MFMAs (B amortized over two
// row tiles). Cross-wave reduce in LDS, then 32 rows x 16 cells = 512
// threads run the per-cell Sinkhorn and write out directly.
// (identical to R13 except f2bf replaces inline-asm cvt_pk)
// ------------------------------------------------------------------
__global__ __launch_bounds__(1024) void mhc_full(
    const float* __restrict__ x,
    const uint4* __restrict__ packed,
    const float* __restrict__ b_pre,
    const float* __restrict__ b_post,
    const float* __restrict__ b_res,
    const float* __restrict__ a_pre,
    const float* __restrict__ a_post,
    const float* __restrict__ a_res,
    float* __restrict__ out)
{
    __shared__ float red[NWAVE * 2 * 9 * 64];   // 73.7 KB

    const int t    = threadIdx.x;
    const int wave = t >> 6;               // 0..15 = k-slice
    const int lane = t & 63;
    const int g    = blockIdx.x;           // row group 0..255

    const int row0 = g * BM + (lane & 15);         // tile 0 row
    const float* xr0 = x + (size_t)row0 * KDIM + wave * 256 + 8 * (lane >> 4);
    const float* xr1 = xr0 + (size_t)16 * KDIM;    // tile 1 row
    const uint4* pb = packed + wave * (NSW * 2 * 64);

    f32x4 acc00 = {0.f, 0.f, 0.f, 0.f};
    f32x4 acc01 = {0.f, 0.f, 0.f, 0.f};
    f32x4 acc10 = {0.f, 0.f, 0.f, 0.f};
    f32x4 acc11 = {0.f, 0.f, 0.f, 0.f};
    float ssqt0 = 0.f, ssqt1 = 0.f;

    #pragma unroll 4
    for (int s = 0; s < NSW; ++s) {
        const float4 p0 = *(const float4*)(xr0 + 32 * s);
        const float4 p1 = *(const float4*)(xr0 + 32 * s + 4);
        const float4 q0 = *(const float4*)(xr1 + 32 * s);
        const float4 q1 = *(const float4*)(xr1 + 32 * s + 4);
        BF b0, b1;
        b0.u4 = pb[(s * 2 + 0) * 64 + lane];
        b1.u4 = pb[(s * 2 + 1) * 64 + lane];

        ssqt0 = fmaf(p0.x, p0.x, ssqt0);
        ssqt0 = fmaf(p0.y, p0.y, ssqt0);
        ssqt0 = fmaf(p0.z, p0.z, ssqt0);
        ssqt0 = fmaf(p0.w, p0.w, ssqt0);
        ssqt0 = fmaf(p1.x, p1.x, ssqt0);
        ssqt0 = fmaf(p1.y, p1.y, ssqt0);
        ssqt0 = fmaf(p1.z, p1.z, ssqt0);
        ssqt0 = fmaf(p1.w, p1.w, ssqt0);
        ssqt1 = fmaf(q0.x, q0.x, ssqt1);
        ssqt1 = fmaf(q0.y, q0.y, ssqt1);
        ssqt1 = fmaf(q0.z, q0.z, ssqt1);
        ssqt1 = fmaf(q0.w, q0.w, ssqt1);
        ssqt1 = fmaf(q1.x, q1.x, ssqt1);
        ssqt1 = fmaf(q1.y, q1.y, ssqt1);
        ssqt1 = fmaf(q1.z, q1.z, ssqt1);
        ssqt1 = fmaf(q1.w, q1.w, ssqt1);

        BF af0, af1;
        af0.u4.x = pkbf(p0.x, p0.y);
        af0.u4.y = pkbf(p0.z, p0.w);
        af0.u4.z = pkbf(p1.x, p1.y);
        af0.u4.w = pkbf(p1.z, p1.w);
        af1.u4.x = pkbf(q0.x, q0.y);
        af1.u4.y = pkbf(q0.z, q0.w);
        af1.u4.z = pkbf(q1.x, q1.y);
        af1.u4.w = pkbf(q1.z, q1.w);

        acc00 = __builtin_amdgcn_mfma_f32_16x16x32_bf16(af0.h, b0.h, acc00, 0, 0, 0);
        acc01 = __builtin_amdgcn_mfma_f32_16x16x32_bf16(af0.h, b1.h, acc01, 0, 0, 0);
        acc10 = __builtin_amdgcn_mfma_f32_16x16x32_bf16(af1.h, b0.h, acc10, 0, 0, 0);
        acc11 = __builtin_amdgcn_mfma_f32_16x16x32_bf16(af1.h, b1.h, acc11, 0, 0, 0);
    }

    // fold the 4 k-offset lane groups (same row across l>>4)
    ssqt0 += __shfl_xor(ssqt0, 16);
    ssqt0 += __shfl_xor(ssqt0, 32);
    ssqt1 += __shfl_xor(ssqt1, 16);
    ssqt1 += __shfl_xor(ssqt1, 32);

    // ---- dump per-wave partials: red[wave][tile][j(9)][lane] ----
    float* myred = red + wave * 1152;
    #pragma unroll
    for (int r = 0; r < 4; ++r) myred[r * 64 + lane] = acc00[r];
    #pragma unroll
    for (int r = 0; r < 4; ++r) myred[(4 + r) * 64 + lane] = acc01[r];
    myred[8 * 64 + lane] = ssqt0;
    #pragma unroll
    for (int r = 0; r < 4; ++r) myred[576 + r * 64 + lane] = acc10[r];
    #pragma unroll
    for (int r = 0; r < 4; ++r) myred[576 + (4 + r) * 64 + lane] = acc11[r];
    myred[576 + 8 * 64 + lane] = ssqt1;
    __syncthreads();

    // ---- reduce 16 wave-slices into slot 0 (1152 sums) ----
    for (int i = t; i < 1152; i += 1024) {
        float s = red[i];
        #pragma unroll
        for (int q = 1; q < NWAVE; ++q)
            s += red[q * 1152 + i];
        red[i] = s;
    }
    __syncthreads();

    // ---- epilogue: 32 rows x 16 cells = threads 0..511 ----
    if (t < 512) {
        const int rr   = t >> 4;          // block row 0..31
        const int cell = t & 15;          // res cell i*4+jc
        const int tile = rr >> 4;
        const int lr   = rr & 15;
        const int gr   = g * BM + rr;
        const float* rb = red + tile * 576;

        const float scale = rsqrtf(rb[8 * 64 + lr] * (1.0f / KDIM) + 1e-6f);
        const int li = 16 * (lr >> 2);
        const int j0 = lr & 3;

        if (cell < 4) {
            const float v = rb[j0 * 64 + li + cell];
            out[gr * 4 + cell] = sigmoidf_(fmaf(a_pre[0] * scale, v, b_pre[cell]));
        } else if (cell < 8) {
            const float v = rb[j0 * 64 + li + cell];
            out[32768 + gr * 4 + (cell - 4)] =
                2.f * sigmoidf_(fmaf(a_post[0] * scale, v, b_post[cell - 4]));
        }

        // res column 8+cell (acc*0 holds cols 0-15, acc*1 cols 16-31)
        const int col   = 8 + cell;
        const int jslot = j0 + (col < 16 ? 0 : 4);
        const float v   = rb[jslot * 64 + (col & 15) + li];
        float m = __expf(fmaf(a_res[0] * scale, v, b_res[cell]));

        for (int it = 0; it < 20; ++it) {
            float s = m + __shfl_xor(m, 1);       // row sum over jc
            s += __shfl_xor(s, 2);
            m /= s;
            float c = m + __shfl_xor(m, 4);       // col sum over i
            c += __shfl_xor(c, 8);
            m /= c;
        }
        out[65536 + gr * 16 + cell] = m;
    }
}

// ------------------------------------------------------------------
// Legacy fallback (tiny ws): R12-style pack consumers, f2bf version.
// ------------------------------------------------------------------
__global__ __launch_bounds__(1024) void mhc_full16(
    const float* __restrict__ x,
    const uint4* __restrict__ packed,
    const float* __restrict__ b_pre,
    const float* __restrict__ b_post,
    const float* __restrict__ b_res,
    const float* __restrict__ a_pre,
    const float* __restrict__ a_post,
    const float* __restrict__ a_res,
    float* __restrict__ out)
{
    __shared__ float red[16 * 9 * 64];

    const int t    = threadIdx.x;
    const int wave = t >> 6;
    const int lane = t & 63;
    const int g    = blockIdx.x;

    const int row = g * 16 + (lane & 15);
    const float* xr = x + (size_t)row * KDIM + wave * 256 + 8 * (lane >> 4);
    const uint4* pb = packed + wave * (8 * 2 * 64);

    f32x4 acc0 = {0.f, 0.f, 0.f, 0.f};
    f32x4 acc1 = {0.f, 0.f, 0.f, 0.f};
    float ssq0 = 0.f, ssq1 = 0.f;

    #pragma unroll 4
    for (int s = 0; s < 8; ++s) {
        const float4 a0 = *(const float4*)(xr + 32 * s);
        const float4 a1 = *(const float4*)(xr + 32 * s + 4);
        ssq0 = fmaf(a0.x, a0.x, ssq0); ssq0 = fmaf(a0.y, a0.y, ssq0);
        ssq0 = fmaf(a0.z, a0.z, ssq0); ssq0 = fmaf(a0.w, a0.w, ssq0);
        ssq1 = fmaf(a1.x, a1.x, ssq1); ssq1 = fmaf(a1.y, a1.y, ssq1);
        ssq1 = fmaf(a1.z, a1.z, ssq1); ssq1 = fmaf(a1.w, a1.w, ssq1);
        BF af;
        af.u4.x = pkbf(a0.x, a0.y);
        af.u4.y = pkbf(a0.z, a0.w);
        af.u4.z = pkbf(a1.x, a1.y);
        af.u4.w = pkbf(a1.z, a1.w);
        BF b0, b1;
        b0.u4 = pb[(s * 2 + 0) * 64 + lane];
        b1.u4 = pb[(s * 2 + 1) * 64 + lane];
        acc0 = __builtin_amdgcn_mfma_f32_16x16x32_bf16(af.h, b0.h, acc0, 0, 0, 0);
        acc1 = __builtin_amdgcn_mfma_f32_16x16x32_bf16(af.h, b1.h, acc1, 0, 0, 0);
    }

    float ssq = ssq0 + ssq1;
    ssq += __shfl_xor(ssq, 16);
    ssq += __shfl_xor(ssq, 32);

    float* myred = red + wave * 576;
    #pragma unroll
    for (int r = 0; r < 4; ++r) myred[r * 64 + lane] = acc0[r];
    #pragma unroll
    for (int r = 0; r < 4; ++r) myred[(4 + r) * 64 + lane] = acc1[r];
    myred[8 * 64 + lane] = ssq;
    __syncthreads();

    if (t < 576) {
        float s = red[t];
        #pragma unroll
        for (int q = 1; q < 16; ++q)
            s += red[q * 576 + t];
        red[t] = s;
    }
    __syncthreads();

    if (t < 256) {
        const int rr   = t >> 4;
        const int cell = t & 15;
        const int gr   = g * 16 + rr;

        const float scale = rsqrtf(red[8 * 64 + rr] * (1.0f / KDIM) + 1e-6f);
        const int li = 16 * (rr >> 2);
        const int j0 = rr & 3;

        if (cell < 4) {
            const float v = red[j0 * 64 + li + cell];
            out[gr * 4 + cell] = sigmoidf_(fmaf(a_pre[0] * scale, v, b_pre[cell]));
        } else if (cell < 8) {
            const float v = red[j0 * 64 + li + cell];
            out[32768 + gr * 4 + (cell - 4)] =
                2.f * sigmoidf_(fmaf(a_post[0] * scale, v, b_post[cell - 4]));
        }

        const int col   = 8 + cell;
        const int jslot = j0 + (col < 16 ? 0 : 4);
        const float v   = red[jslot * 64 + (col & 15) + li];
        float m = __expf(fmaf(a_res[0] * scale, v, b_res[cell]));
        for (int it = 0; it < 20; ++it) {
            float s = m + __shfl_xor(m, 1);
            s += __shfl_xor(s, 2);
            m /= s;
            float c = m + __shfl_xor(m, 4);
            c += __shfl_xor(c, 8);
            m /= c;
        }
        out[65536 + gr * 16 + cell] = m;
    }
}

extern "C" void kernel_launch(void* const* d_in, const int* in_sizes, int n_in,
                              void* d_out, int out_size, void* d_ws, size_t ws_size,
                              hipStream_t stream) {
    const float* x      = (const float*)d_in[0];
    const float* rmsw   = (const float*)d_in[1];
    const float* ppre   = (const float*)d_in[2];
    const float* ppost  = (const float*)d_in[3];
    const float* pres   = (const float*)d_in[4];
    const float* b_pre  = (const float*)d_in[5];
    const float* b_post = (const float*)d_in[6];
    const float* b_res  = (const float*)d_in[7];
    const float* a_pre  = (const float*)d_in[8];
    const float* a_post = (const float*)d_in[9];
    const float* a_res  = (const float*)d_in[10];
    float* out = (float*)d_out;

    uint4* packed = (uint4*)d_ws;   // 256 KB
    hipLaunchKernelGGL(mhc_pack, dim3(32), dim3(512), 0, stream,
                       rmsw, ppre, ppost, pres, packed);
    if (ws_size >= (size_t)16384 * 16) {
        hipLaunchKernelGGL(mhc_full, dim3(256), dim3(1024), 0, stream,
                           x, packed, b_pre, b_post, b_res,
                           a_pre, a_post, a_res, out);
    } else {
        hipLaunchKernelGGL(mhc_full16, dim3(512), dim3(1024), 0, stream,
                           x, packed, b_pre, b_post, b_res,
                           a_pre, a_post, a_res, out);
    }
}

// Round 17
// 38.357 us; speedup vs baseline: 2.5221x; 1.1818x over previous
//
#include <hip/hip_runtime.h>
#include <math.h>

#define ROWS_TOTAL 8192
#define KDIM 4096
#define NJ 25

typedef __attribute__((ext_vector_type(8))) short bf16x8;
typedef __attribute__((ext_vector_type(4))) float f32x4;

// gfx950 packed f32->bf16 (RNE); dst.lo=bf16(lo), dst.hi=bf16(hi).
// NOTE: asm cvt_pk beat pure-C f2bf in this structure (R13=41.0 vs
// R15=45.3) -- m240's warning is regime-conditional here.
__device__ __forceinline__ unsigned cvt_pk_bf16(float lo, float hi) {
    unsigned r;
    asm("v_cvt_pk_bf16_f32 %0, %1, %2" : "=v"(r) : "v"(lo), "v"(hi));
    return r;
}

union BF { uint4 u4; bf16x8 h; };

__device__ __forceinline__ float sigmoidf_(float z) {
    return 1.f / (1.f + __expf(-z));
}

// ------------------------------------------------------------------
// Kernel 0: pack B = (rmsw * phi) into MFMA-fragment order, bf16.
// 128 blocks x 128 threads (one frag per thread).
// ------------------------------------------------------------------
__global__ __launch_bounds__(128) void mhc_pack(
    const float* __restrict__ rmsw,
    const float* __restrict__ phi_pre,
    const float* __restrict__ phi_post,
    const float* __restrict__ phi_res,
    uint4* __restrict__ packed)
{
    const int fid = blockIdx.x * 128 + threadIdx.x;   // 0..16383
    const int s   = fid >> 7;
    const int n   = (fid >> 6) & 1;
    const int ln  = fid & 63;
    const int col = n * 16 + (ln & 15);
    const int kl  = s * 32 + 8 * (ln >> 4);
    float v[8];
    #pragma unroll
    for (int j = 0; j < 8; ++j) {
        const int k = kl + j;
        float vv = 0.f;
        if (col < 4)       vv = rmsw[k] * phi_pre[k * 4 + col];
        else if (col < 8)  vv = rmsw[k] * phi_post[k * 4 + (col - 4)];
        else if (col < 24) vv = rmsw[k] * phi_res[k * 16 + (col - 8)];
        v[j] = vv;
    }
    uint4 pk;
    pk.x = cvt_pk_bf16(v[0], v[1]);
    pk.y = cvt_pk_bf16(v[2], v[3]);
    pk.z = cvt_pk_bf16(v[4], v[5]);
    pk.w = cvt_pk_bf16(v[6], v[7]);
    packed[fid] = pk;
}

// ------------------------------------------------------------------
// Kernel 1: full-K fused projection + epilogue. 512 blocks x 512 thr
// (BM=16, 8 waves; wave w covers k in [512w, 512w+512), NSW=16).
// R16 bug fixed: cross-wave reduce must loop i = t; i < 576; i += 512
// (512-thread block vs 576 reduce slots -- the tail slots are ssq;
// leaving them unreduced made scale wrong by sqrt(8), absmax 2.5e-2).
// No launch-bounds min-waves (R1/R7/R14 trap).
// ------------------------------------------------------------------
__global__ __launch_bounds__(512) void mhc_full(
    const float* __restrict__ x,
    const uint4* __restrict__ packed,
    const float* __restrict__ b_pre,
    const float* __restrict__ b_post,
    const float* __restrict__ b_res,
    const float* __restrict__ a_pre,
    const float* __restrict__ a_post,
    const float* __restrict__ a_res,
    float* __restrict__ out)
{
    __shared__ float red[8 * 9 * 64];   // 18.4 KB

    const int t    = threadIdx.x;
    const int wave = t >> 6;               // 0..7 = k-slice (512 k each)
    const int lane = t & 63;
    const int g    = blockIdx.x;           // row group 0..511

    const int row = g * 16 + (lane & 15);
    const float* xr = x + (size_t)row * KDIM + wave * 512 + 8 * (lane >> 4);
    const uint4* pb = packed + (wave * 16) * (2 * 64);   // K-steps 16w..16w+15

    f32x4 acc0 = {0.f, 0.f, 0.f, 0.f};
    f32x4 acc1 = {0.f, 0.f, 0.f, 0.f};
    float ssq0 = 0.f, ssq1 = 0.f;

    #pragma unroll 4
    for (int s = 0; s < 16; ++s) {
        const float4 a0 = *(const float4*)(xr + 32 * s);
        const float4 a1 = *(const float4*)(xr + 32 * s + 4);
        ssq0 = fmaf(a0.x, a0.x, ssq0);
        ssq0 = fmaf(a0.y, a0.y, ssq0);
        ssq0 = fmaf(a0.z, a0.z, ssq0);
        ssq0 = fmaf(a0.w, a0.w, ssq0);
        ssq1 = fmaf(a1.x, a1.x, ssq1);
        ssq1 = fmaf(a1.y, a1.y, ssq1);
        ssq1 = fmaf(a1.z, a1.z, ssq1);
        ssq1 = fmaf(a1.w, a1.w, ssq1);
        BF af;
        af.u4.x = cvt_pk_bf16(a0.x, a0.y);
        af.u4.y = cvt_pk_bf16(a0.z, a0.w);
        af.u4.z = cvt_pk_bf16(a1.x, a1.y);
        af.u4.w = cvt_pk_bf16(a1.z, a1.w);
        BF b0, b1;
        b0.u4 = pb[(s * 2 + 0) * 64 + lane];
        b1.u4 = pb[(s * 2 + 1) * 64 + lane];
        acc0 = __builtin_amdgcn_mfma_f32_16x16x32_bf16(af.h, b0.h, acc0, 0, 0, 0);
        acc1 = __builtin_amdgcn_mfma_f32_16x16x32_bf16(af.h, b1.h, acc1, 0, 0, 0);
    }

    // fold the 4 k-offset lane groups (same row across l>>4)
    float ssq = ssq0 + ssq1;
    ssq += __shfl_xor(ssq, 16);
    ssq += __shfl_xor(ssq, 32);

    // ---- dump per-wave partials: red[wave][j(9)][lane] ----
    float* myred = red + wave * 576;
    #pragma unroll
    for (int r = 0; r < 4; ++r) myred[r * 64 + lane] = acc0[r];
    #pragma unroll
    for (int r = 0; r < 4; ++r) myred[(4 + r) * 64 + lane] = acc1[r];
    myred[8 * 64 + lane] = ssq;
    __syncthreads();

    // ---- reduce 8 wave-slices into slot 0 (576 sums, 512 threads) ----
    for (int i = t; i < 576; i += 512) {
        float s = red[i];
        #pragma unroll
        for (int q = 1; q < 8; ++q)
            s += red[q * 576 + i];
        red[i] = s;
    }
    __syncthreads();

    // ---- epilogue: 16 rows x 16 cells = threads 0..255 ----
    // C/D layout: value(row rr, col c) = red[jslot*64 + li],
    //   jslot = (rr&3) + (c<16 ? 0 : 4), li = (c&15) + 16*(rr>>2).
    if (t < 256) {
        const int rr   = t >> 4;          // local row 0..15
        const int cell = t & 15;          // res cell i*4+jc
        const int gr   = g * 16 + rr;

        const float scale = rsqrtf(red[8 * 64 + rr] * (1.0f / KDIM) + 1e-6f);
        const int li = 16 * (rr >> 2);
        const int j0 = rr & 3;

        if (cell < 4) {
            const float v = red[j0 * 64 + li + cell];
            out[gr * 4 + cell] = sigmoidf_(fmaf(a_pre[0] * scale, v, b_pre[cell]));
        } else if (cell < 8) {
            const float v = red[j0 * 64 + li + cell];
            out[32768 + gr * 4 + (cell - 4)] =
                2.f * sigmoidf_(fmaf(a_post[0] * scale, v, b_post[cell - 4]));
        }

        // res column 8+cell (acc0 holds cols 0-15, acc1 cols 16-31)
        const int col   = 8 + cell;
        const int jslot = j0 + (col < 16 ? 0 : 4);
        const float v   = red[jslot * 64 + (col & 15) + li];
        float m = __expf(fmaf(a_res[0] * scale, v, b_res[cell]));

        for (int it = 0; it < 20; ++it) {
            float s = m + __shfl_xor(m, 1);       // row sum over jc
            s += __shfl_xor(s, 2);
            m /= s;
            float c = m + __shfl_xor(m, 4);       // col sum over i
            c += __shfl_xor(c, 8);
            m /= c;
        }
        out[65536 + gr * 16 + cell] = m;
    }
}

extern "C" void kernel_launch(void* const* d_in, const int* in_sizes, int n_in,
                              void* d_out, int out_size, void* d_ws, size_t ws_size,
                              hipStream_t stream) {
    const float* x      = (const float*)d_in[0];
    const float* rmsw   = (const float*)d_in[1];
    const float* ppre   = (const float*)d_in[2];
    const float* ppost  = (const float*)d_in[3];
    const float* pres   = (const float*)d_in[4];
    const float* b_pre  = (const float*)d_in[5];
    const float* b_post = (const float*)d_in[6];
    const float* b_res  = (const float*)d_in[7];
    const float* a_pre  = (const float*)d_in[8];
    const float* a_post = (const float*)d_in[9];
    const float* a_res  = (const float*)d_in[10];
    float* out = (float*)d_out;

    uint4* packed = (uint4*)d_ws;   // 256 KB
    hipLaunchKernelGGL(mhc_pack, dim3(128), dim3(128), 0, stream,
                       rmsw, ppre, ppost, pres, packed);
    hipLaunchKernelGGL(mhc_full, dim3(512), dim3(512), 0, stream,
                       x, packed, b_pre, b_post, b_res,
                       a_pre, a_post, a_res, out);
}

// Round 18
// 37.427 us; speedup vs baseline: 2.5848x; 1.0249x over previous
//
#include <hip/hip_runtime.h>
#include <math.h>

#define ROWS_TOTAL 8192
#define KDIM 4096
#define NJ 25
#define BM 32            // rows per block: two 16-row tiles per wave
#define NSW 16           // K-steps of 32 per wave (8 waves x 512 k)

typedef __attribute__((ext_vector_type(8))) short bf16x8;
typedef __attribute__((ext_vector_type(4))) float f32x4;

// gfx950 packed f32->bf16 (RNE); dst.lo=bf16(lo), dst.hi=bf16(hi).
// asm cvt_pk beat pure-C f2bf here (R13=41.0 vs R15=45.3).
__device__ __forceinline__ unsigned cvt_pk_bf16(float lo, float hi) {
    unsigned r;
    asm("v_cvt_pk_bf16_f32 %0, %1, %2" : "=v"(r) : "v"(lo), "v"(hi));
    return r;
}

union BF { uint4 u4; bf16x8 h; };

__device__ __forceinline__ float sigmoidf_(float z) {
    return 1.f / (1.f + __expf(-z));
}

// ------------------------------------------------------------------
// Kernel 0: pack B = (rmsw * phi) into MFMA-fragment order, bf16.
// 128 blocks x 128 threads (one frag per thread). (unchanged R17)
// ------------------------------------------------------------------
__global__ __launch_bounds__(128) void mhc_pack(
    const float* __restrict__ rmsw,
    const float* __restrict__ phi_pre,
    const float* __restrict__ phi_post,
    const float* __restrict__ phi_res,
    uint4* __restrict__ packed)
{
    const int fid = blockIdx.x * 128 + threadIdx.x;   // 0..16383
    const int s   = fid >> 7;
    const int n   = (fid >> 6) & 1;
    const int ln  = fid & 63;
    const int col = n * 16 + (ln & 15);
    const int kl  = s * 32 + 8 * (ln >> 4);
    float v[8];
    #pragma unroll
    for (int j = 0; j < 8; ++j) {
        const int k = kl + j;
        float vv = 0.f;
        if (col < 4)       vv = rmsw[k] * phi_pre[k * 4 + col];
        else if (col < 8)  vv = rmsw[k] * phi_post[k * 4 + (col - 4)];
        else if (col < 24) vv = rmsw[k] * phi_res[k * 16 + (col - 8)];
        v[j] = vv;
    }
    uint4 pk;
    pk.x = cvt_pk_bf16(v[0], v[1]);
    pk.y = cvt_pk_bf16(v[2], v[3]);
    pk.z = cvt_pk_bf16(v[4], v[5]);
    pk.w = cvt_pk_bf16(v[6], v[7]);
    packed[fid] = pk;
}

// ------------------------------------------------------------------
// Kernel 1: full-K fused projection + epilogue. 256 blocks x 512 thr.
// BM=32: wave w covers k in [512w, 512w+512) for TWO 16-row tiles
// against the same B fragments -> B L2-traffic halves vs R17 and
// B-load instructions per x-byte halve. unroll 2 (6 loads/step -> ~48
// load VGPRs) to keep VGPR<=~96 and ~20 waves/CU (R13's BM=32 failed
// only at 1024-thr occupancy granularity).
// Cross-wave reduce in LDS (36.9 KB), then 32 rows x 16 cells = 512
// threads run per-cell Sinkhorn. No launch-bounds min-waves (R1/R7).
// ------------------------------------------------------------------
__global__ __launch_bounds__(512) void mhc_full(
    const float* __restrict__ x,
    const uint4* __restrict__ packed,
    const float* __restrict__ b_pre,
    const float* __restrict__ b_post,
    const float* __restrict__ b_res,
    const float* __restrict__ a_pre,
    const float* __restrict__ a_post,
    const float* __restrict__ a_res,
    float* __restrict__ out)
{
    __shared__ float red[8 * 2 * 9 * 64];   // 36.9 KB

    const int t    = threadIdx.x;
    const int wave = t >> 6;               // 0..7 = k-slice (512 k each)
    const int lane = t & 63;
    const int g    = blockIdx.x;           // row group 0..255

    const int row0 = g * BM + (lane & 15);
    const float* xr0 = x + (size_t)row0 * KDIM + wave * 512 + 8 * (lane >> 4);
    const float* xr1 = xr0 + (size_t)16 * KDIM;
    const uint4* pb = packed + (wave * NSW) * (2 * 64);

    f32x4 acc00 = {0.f, 0.f, 0.f, 0.f};
    f32x4 acc01 = {0.f, 0.f, 0.f, 0.f};
    f32x4 acc10 = {0.f, 0.f, 0.f, 0.f};
    f32x4 acc11 = {0.f, 0.f, 0.f, 0.f};
    float ssqt0 = 0.f, ssqt1 = 0.f;

    #pragma unroll 2
    for (int s = 0; s < NSW; ++s) {
        const float4 p0 = *(const float4*)(xr0 + 32 * s);
        const float4 p1 = *(const float4*)(xr0 + 32 * s + 4);
        const float4 q0 = *(const float4*)(xr1 + 32 * s);
        const float4 q1 = *(const float4*)(xr1 + 32 * s + 4);
        BF b0, b1;
        b0.u4 = pb[(s * 2 + 0) * 64 + lane];
        b1.u4 = pb[(s * 2 + 1) * 64 + lane];

        ssqt0 = fmaf(p0.x, p0.x, ssqt0);
        ssqt0 = fmaf(p0.y, p0.y, ssqt0);
        ssqt0 = fmaf(p0.z, p0.z, ssqt0);
        ssqt0 = fmaf(p0.w, p0.w, ssqt0);
        ssqt0 = fmaf(p1.x, p1.x, ssqt0);
        ssqt0 = fmaf(p1.y, p1.y, ssqt0);
        ssqt0 = fmaf(p1.z, p1.z, ssqt0);
        ssqt0 = fmaf(p1.w, p1.w, ssqt0);
        ssqt1 = fmaf(q0.x, q0.x, ssqt1);
        ssqt1 = fmaf(q0.y, q0.y, ssqt1);
        ssqt1 = fmaf(q0.z, q0.z, ssqt1);
        ssqt1 = fmaf(q0.w, q0.w, ssqt1);
        ssqt1 = fmaf(q1.x, q1.x, ssqt1);
        ssqt1 = fmaf(q1.y, q1.y, ssqt1);
        ssqt1 = fmaf(q1.z, q1.z, ssqt1);
        ssqt1 = fmaf(q1.w, q1.w, ssqt1);

        BF af0, af1;
        af0.u4.x = cvt_pk_bf16(p0.x, p0.y);
        af0.u4.y = cvt_pk_bf16(p0.z, p0.w);
        af0.u4.z = cvt_pk_bf16(p1.x, p1.y);
        af0.u4.w = cvt_pk_bf16(p1.z, p1.w);
        af1.u4.x = cvt_pk_bf16(q0.x, q0.y);
        af1.u4.y = cvt_pk_bf16(q0.z, q0.w);
        af1.u4.z = cvt_pk_bf16(q1.x, q1.y);
        af1.u4.w = cvt_pk_bf16(q1.z, q1.w);

        acc00 = __builtin_amdgcn_mfma_f32_16x16x32_bf16(af0.h, b0.h, acc00, 0, 0, 0);
        acc01 = __builtin_amdgcn_mfma_f32_16x16x32_bf16(af0.h, b1.h, acc01, 0, 0, 0);
        acc10 = __builtin_amdgcn_mfma_f32_16x16x32_bf16(af1.h, b0.h, acc10, 0, 0, 0);
        acc11 = __builtin_amdgcn_mfma_f32_16x16x32_bf16(af1.h, b1.h, acc11, 0, 0, 0);
    }

    // fold the 4 k-offset lane groups (same row across l>>4)
    ssqt0 += __shfl_xor(ssqt0, 16);
    ssqt0 += __shfl_xor(ssqt0, 32);
    ssqt1 += __shfl_xor(ssqt1, 16);
    ssqt1 += __shfl_xor(ssqt1, 32);

    // ---- dump per-wave partials: red[wave][tile][j(9)][lane] ----
    float* myred = red + wave * 1152;
    #pragma unroll
    for (int r = 0; r < 4; ++r) myred[r * 64 + lane] = acc00[r];
    #pragma unroll
    for (int r = 0; r < 4; ++r) myred[(4 + r) * 64 + lane] = acc01[r];
    myred[8 * 64 + lane] = ssqt0;
    #pragma unroll
    for (int r = 0; r < 4; ++r) myred[576 + r * 64 + lane] = acc10[r];
    #pragma unroll
    for (int r = 0; r < 4; ++r) myred[576 + (4 + r) * 64 + lane] = acc11[r];
    myred[576 + 8 * 64 + lane] = ssqt1;
    __syncthreads();

    // ---- reduce 8 wave-slices into slot 0 (1152 sums, 512 threads) ----
    for (int i = t; i < 1152; i += 512) {
        float s = red[i];
        #pragma unroll
        for (int q = 1; q < 8; ++q)
            s += red[q * 1152 + i];
        red[i] = s;
    }
    __syncthreads();

    // ---- epilogue: 32 rows x 16 cells = all 512 threads ----
    // value(local row lr, col c) = red[tile*576 + jslot*64 + li],
    //   jslot = (lr&3) + (c<16 ? 0 : 4), li = (c&15) + 16*(lr>>2).
    {
        const int rr   = t >> 4;          // block row 0..31
        const int cell = t & 15;          // res cell i*4+jc
        const int tile = rr >> 4;
        const int lr   = rr & 15;
        const int gr   = g * BM + rr;
        const float* rb = red + tile * 576;

        const float scale = rsqrtf(rb[8 * 64 + lr] * (1.0f / KDIM) + 1e-6f);
        const int li = 16 * (lr >> 2);
        const int j0 = lr & 3;

        if (cell < 4) {
            const float v = rb[j0 * 64 + li + cell];
            out[gr * 4 + cell] = sigmoidf_(fmaf(a_pre[0] * scale, v, b_pre[cell]));
        } else if (cell < 8) {
            const float v = rb[j0 * 64 + li + cell];
            out[32768 + gr * 4 + (cell - 4)] =
                2.f * sigmoidf_(fmaf(a_post[0] * scale, v, b_post[cell - 4]));
        }

        // res column 8+cell (acc*0 holds cols 0-15, acc*1 cols 16-31)
        const int col   = 8 + cell;
        const int jslot = j0 + (col < 16 ? 0 : 4);
        const float v   = rb[jslot * 64 + (col & 15) + li];
        float m = __expf(fmaf(a_res[0] * scale, v, b_res[cell]));

        for (int it = 0; it < 20; ++it) {
            float s = m + __shfl_xor(m, 1);       // row sum over jc
            s += __shfl_xor(s, 2);
            m /= s;
            float c = m + __shfl_xor(m, 4);       // col sum over i
            c += __shfl_xor(c, 8);
            m /= c;
        }
        out[65536 + gr * 16 + cell] = m;
    }
}

extern "C" void kernel_launch(void* const* d_in, const int* in_sizes, int n_in,
                              void* d_out, int out_size, void* d_ws, size_t ws_size,
                              hipStream_t stream) {
    const float* x      = (const float*)d_in[0];
    const float* rmsw   = (const float*)d_in[1];
    const float* ppre   = (const float*)d_in[2];
    const float* ppost  = (const float*)d_in[3];
    const float* pres   = (const float*)d_in[4];
    const float* b_pre  = (const float*)d_in[5];
    const float* b_post = (const float*)d_in[6];
    const float* b_res  = (const float*)d_in[7];
    const float* a_pre  = (const float*)d_in[8];
    const float* a_post = (const float*)d_in[9];
    const float* a_res  = (const float*)d_in[10];
    float* out = (float*)d_out;

    uint4* packed = (uint4*)d_ws;   // 256 KB
    hipLaunchKernelGGL(mhc_pack, dim3(128), dim3(128), 0, stream,
                       rmsw, ppre, ppost, pres, packed);
    hipLaunchKernelGGL(mhc_full, dim3(256), dim3(512), 0, stream,
                       x, packed, b_pre, b_post, b_res,
                       a_pre, a_post, a_res, out);
}